// Round 4
// baseline (204.947 us; speedup 1.0000x reference)
//
#include <hip/hip_runtime.h>

// Segment mean-pooling: feats [B,S,H] f32, segment_ids [B,S] i32 sorted
// non-decreasing in [0,G). Outputs flat-concat: grouped [B,G,H] f32, then
// counts [B,G] written as float values.
#define BB 8
#define SS 8192
#define HH 512
#define GG 1024
#define CHUNK 64   // tokens per block: uniform work => no straggler block

typedef float f32x4 __attribute__((ext_vector_type(4)));

// Kernel A: offsets[b][g] = lower_bound(ids[b], g) for g in [0, G].
__global__ __launch_bounds__(256) void seg_offsets_kernel(
    const int* __restrict__ ids,
    int*       __restrict__ offsets)   // [B][G+1]
{
    const int tid = blockIdx.x * 256 + threadIdx.x;  // 0 .. B*S-1
    const int b = tid / SS;
    const int s = tid - b * SS;
    const int* __restrict__ row = ids + (size_t)b * SS;
    int* __restrict__ offs = offsets + (size_t)b * (GG + 1);

    const int cur  = row[s];
    const int prev = (s > 0) ? row[s - 1] : -1;
    for (int g = prev + 1; g <= cur; ++g) offs[g] = s;
    if (s == SS - 1) {
        for (int g = cur + 1; g <= GG; ++g) offs[g] = SS;
    }
}

// Zero-fill grouped (empty groups + atomic accumulation targets need 0).
__global__ __launch_bounds__(256) void zero_kernel(f32x4* __restrict__ p) {
    const size_t i = (size_t)blockIdx.x * 256 + threadIdx.x;  // B*G*H/4 elems
    __builtin_nontemporal_store((f32x4)0.f, &p[i]);
}

// Counts output (as float values in the flat f32 out buffer).
__global__ __launch_bounds__(256) void counts_kernel(
    const int* __restrict__ offsets, float* __restrict__ counts) {
    const int i = blockIdx.x * 256 + threadIdx.x;  // 0 .. B*G-1
    const int b = i >> 10, g = i & (GG - 1);
    const int* offs = offsets + (size_t)b * (GG + 1);
    counts[i] = (float)(offs[g + 1] - offs[g]);
}

// Kernel B: one block per uniform CHUNK-token span. 128 lanes * float4 =
// 2048B = one full H row per token, perfectly coalesced. Runs of equal
// group id inside the chunk come from precomputed offsets (wave-uniform,
// L2-cached). Partial sums are pre-scaled by 1/full_count; groups fully
// inside the chunk are direct-stored, straddling groups atomically added.
__global__ __launch_bounds__(128) void group_mean_chunk_kernel(
    const f32x4* __restrict__ feats,
    const int*   __restrict__ ids,
    const int*   __restrict__ offsets,
    float*       __restrict__ grouped)
{
    const int c = blockIdx.x;           // chunk within batch row
    const int b = blockIdx.y;
    const int t = threadIdx.x;          // 0..127
    const int s0 = c * CHUNK, s1 = s0 + CHUNK;

    const int* __restrict__ offs = offsets + (size_t)b * (GG + 1);
    const f32x4* __restrict__ fb = feats + (size_t)b * SS * (HH / 4);

    int g   = ids[(size_t)b * SS + s0];   // group of first token (uniform)
    int cur = offs[g];                    // group start (<= s0)
    while (cur < s1) {
        const int nxt = offs[g + 1];
        const int rl = cur > s0 ? cur : s0;
        const int rh = nxt < s1 ? nxt : s1;
        if (rh > rl) {
            const int n = nxt - cur;              // full group length (>=1)
            const float inv = 1.0f / (float)n;
            f32x4 a0 = 0.f, a1 = 0.f, a2 = 0.f, a3 = 0.f;
            int s = rl;
            for (; s + 3 < rh; s += 4) {
                f32x4 v0 = __builtin_nontemporal_load(&fb[(size_t)(s    ) * (HH / 4) + t]);
                f32x4 v1 = __builtin_nontemporal_load(&fb[(size_t)(s + 1) * (HH / 4) + t]);
                f32x4 v2 = __builtin_nontemporal_load(&fb[(size_t)(s + 2) * (HH / 4) + t]);
                f32x4 v3 = __builtin_nontemporal_load(&fb[(size_t)(s + 3) * (HH / 4) + t]);
                a0 += v0; a1 += v1; a2 += v2; a3 += v3;
            }
            for (; s < rh; ++s)
                a0 += __builtin_nontemporal_load(&fb[(size_t)s * (HH / 4) + t]);
            const f32x4 r = ((a0 + a1) + (a2 + a3)) * inv;

            float* __restrict__ orow =
                grouped + ((size_t)b * GG + g) * HH + t * 4;
            if (cur >= s0 && nxt <= s1) {
                // sole owner: direct vector store
                *(f32x4*)orow = r;
            } else {
                unsafeAtomicAdd(orow + 0, r.x);
                unsafeAtomicAdd(orow + 1, r.y);
                unsafeAtomicAdd(orow + 2, r.z);
                unsafeAtomicAdd(orow + 3, r.w);
            }
        }
        cur = nxt; ++g;
    }
}

extern "C" void kernel_launch(void* const* d_in, const int* in_sizes, int n_in,
                              void* d_out, int out_size, void* d_ws, size_t ws_size,
                              hipStream_t stream) {
    const float* feats = (const float*)d_in[0];
    const int*   ids   = (const int*)d_in[1];
    float* grouped = (float*)d_out;
    float* counts  = grouped + (size_t)BB * GG * HH;
    int*   offsets = (int*)d_ws;   // B*(G+1) ints

    zero_kernel<<<(BB * GG * (HH / 4)) / 256, 256, 0, stream>>>((f32x4*)grouped);
    seg_offsets_kernel<<<(BB * SS) / 256, 256, 0, stream>>>(ids, offsets);
    counts_kernel<<<(BB * GG) / 256, 256, 0, stream>>>(offsets, counts);

    dim3 grid(SS / CHUNK, BB);
    group_mean_chunk_kernel<<<grid, 128, 0, stream>>>(
        (const f32x4*)feats, ids, offsets, grouped);
}

// Round 5
// 190.229 us; speedup vs baseline: 1.0774x; 1.0774x over previous
//
#include <hip/hip_runtime.h>

// Segment mean-pooling: feats [B,S,H] f32, segment_ids [B,S] i32 sorted
// non-decreasing in [0,G). Outputs flat-concat: grouped [B,G,H] f32, then
// counts [B,G] written as float values.
#define BB 8
#define SS 8192
#define HH 512
#define GG 1024
#define GPB 2   // groups per block: 4096 blocks = 16 blocks/CU = full 32-wave occupancy

typedef float f32x4 __attribute__((ext_vector_type(4)));

// Kernel A: offsets[b][g] = lower_bound(ids[b], g) for g in [0, G].
// Sorted ids => each offset written exactly once (boundary token writes it).
__global__ __launch_bounds__(256) void seg_offsets_kernel(
    const int* __restrict__ ids,
    int*       __restrict__ offsets)   // [B][G+1]
{
    const int tid = blockIdx.x * 256 + threadIdx.x;  // 0 .. B*S-1
    const int b = tid / SS;
    const int s = tid - b * SS;
    const int* __restrict__ row = ids + (size_t)b * SS;
    int* __restrict__ offs = offsets + (size_t)b * (GG + 1);

    const int cur  = row[s];
    const int prev = (s > 0) ? row[s - 1] : -1;
    for (int g = prev + 1; g <= cur; ++g) offs[g] = s;
    if (s == SS - 1) {
        for (int g = cur + 1; g <= GG; ++g) offs[g] = SS;
    }
}

// Kernel B: one block per (b, 2 consecutive groups). 128 lanes * float4 =
// 2048B = full H row, perfectly coalesced per token. Unroll x4 + NT loads.
// __launch_bounds__(128, 8): cap VGPRs <=64 so 8 waves/SIMD (32/CU) fit;
// grid 4096 = 16 blocks/CU = one fully-occupied residency round.
__global__ __launch_bounds__(128, 8) void group_mean_kernel(
    const f32x4* __restrict__ feats,
    const int*   __restrict__ offsets,
    f32x4*       __restrict__ grouped,
    float*       __restrict__ counts)
{
    const int g0 = blockIdx.x * GPB;
    const int b  = blockIdx.y;
    const int t  = threadIdx.x;  // 0..127

    const int* __restrict__ offs = offsets + (size_t)b * (GG + 1) + g0;
    int o[GPB + 1];
    #pragma unroll
    for (int i = 0; i < GPB + 1; ++i) o[i] = offs[i];

    const f32x4* __restrict__ fb = feats + (size_t)b * SS * (HH / 4);

    #pragma unroll
    for (int i = 0; i < GPB; ++i) {
        const int lo = o[i], hi = o[i + 1];
        const int n = hi - lo;
        f32x4 a0 = 0.f, a1 = 0.f, a2 = 0.f, a3 = 0.f;
        int s = lo;
        for (; s + 3 < hi; s += 4) {
            f32x4 v0 = __builtin_nontemporal_load(&fb[(size_t)(s    ) * (HH / 4) + t]);
            f32x4 v1 = __builtin_nontemporal_load(&fb[(size_t)(s + 1) * (HH / 4) + t]);
            f32x4 v2 = __builtin_nontemporal_load(&fb[(size_t)(s + 2) * (HH / 4) + t]);
            f32x4 v3 = __builtin_nontemporal_load(&fb[(size_t)(s + 3) * (HH / 4) + t]);
            a0 += v0; a1 += v1; a2 += v2; a3 += v3;
        }
        for (; s < hi; ++s) {
            a0 += __builtin_nontemporal_load(&fb[(size_t)s * (HH / 4) + t]);
        }
        const float inv = (n > 0) ? (1.0f / (float)n) : 0.0f;
        f32x4 r = ((a0 + a1) + (a2 + a3)) * inv;
        __builtin_nontemporal_store(r, &grouped[((size_t)b * GG + g0 + i) * (HH / 4) + t]);
        if (t == 0) counts[(size_t)b * GG + g0 + i] = (float)n;
    }
}

extern "C" void kernel_launch(void* const* d_in, const int* in_sizes, int n_in,
                              void* d_out, int out_size, void* d_ws, size_t ws_size,
                              hipStream_t stream) {
    const float* feats = (const float*)d_in[0];
    const int*   ids   = (const int*)d_in[1];
    float* grouped = (float*)d_out;
    float* counts  = grouped + (size_t)BB * GG * HH;
    int*   offsets = (int*)d_ws;   // B*(G+1) ints

    seg_offsets_kernel<<<(BB * SS) / 256, 256, 0, stream>>>(ids, offsets);
    dim3 grid(GG / GPB, BB);
    group_mean_kernel<<<grid, 128, 0, stream>>>((const f32x4*)feats, offsets,
                                                (f32x4*)grouped, counts);
}